// Round 1
// baseline (305.383 us; speedup 1.0000x reference)
//
#include <hip/hip_runtime.h>
#include <stdint.h>

#define FDIM 256
#define KDIM 1024   // 4*F : [x | h | Tx1 | Tx2]

typedef __attribute__((ext_vector_type(8))) short short8;
typedef __attribute__((ext_vector_type(4))) float floatx4;

#define GLOBAL_AS __attribute__((address_space(1)))
#define LDS_AS    __attribute__((address_space(3)))

static __device__ __forceinline__ unsigned short f2bf(float f) {
    unsigned int u = __float_as_uint(f);
    unsigned int r = (u + 0x7FFFu + ((u >> 16) & 1u)) >> 16;
    return (unsigned short)r;
}
static __device__ __forceinline__ float bf2f(unsigned short s) {
    return __uint_as_float(((unsigned int)s) << 16);
}
static __device__ __forceinline__ float sig(float x) {
    return 1.f / (1.f + __expf(-x));
}

// ---------------- setup kernels ----------------

__global__ void k_init(float* deg, int* cnt, int* cur, int n) {
    int i = blockIdx.x * blockDim.x + threadIdx.x;
    if (i < n) { deg[i] = 0.f; cnt[i] = 0; cur[i] = 0; }
}

__global__ void k_degcnt(const int* __restrict__ src, const int* __restrict__ dst,
                         const float* __restrict__ ew, float* deg, int* cnt, int e) {
    int i = blockIdx.x * blockDim.x + threadIdx.x;
    if (i < e) {
        atomicAdd(&deg[src[i]], ew[i]);
        atomicAdd(&cnt[dst[i]], 1);
    }
}

__global__ void k_dis(const float* __restrict__ deg, float* __restrict__ dis, int n) {
    int i = blockIdx.x * blockDim.x + threadIdx.x;
    if (i < n) {
        float d = deg[i];
        dis[i] = d > 0.f ? rsqrtf(fmaxf(d, 1e-12f)) : 0.f;
    }
}

// single-block scan: offs[0]=0, offs[i+1]=sum(cnt[0..i])
__global__ void k_scan(const int* __restrict__ cnt, int* __restrict__ offs, int n) {
    __shared__ int sdata[1024];
    int base = 0;
    for (int start = 0; start < n; start += 1024) {
        int i = start + (int)threadIdx.x;
        int v = (i < n) ? cnt[i] : 0;
        sdata[threadIdx.x] = v;
        __syncthreads();
        for (int o = 1; o < 1024; o <<= 1) {
            int t = (threadIdx.x >= (unsigned)o) ? sdata[threadIdx.x - o] : 0;
            __syncthreads();
            sdata[threadIdx.x] += t;
            __syncthreads();
        }
        if (i < n) offs[i + 1] = base + sdata[threadIdx.x];
        base += sdata[1023];
        __syncthreads();
    }
    if (threadIdx.x == 0) offs[0] = 0;
}

__global__ void k_scatter(const int* __restrict__ src, const int* __restrict__ dst,
                          const float* __restrict__ ew, const float* __restrict__ dis,
                          const int* __restrict__ offs, int* cur,
                          int* __restrict__ csr_src, float* __restrict__ csr_w, int e) {
    int i = blockIdx.x * blockDim.x + threadIdx.x;
    if (i < e) {
        int s = src[i], d = dst[i];
        float wn = -dis[s] * ew[i] * dis[d];
        int pos = offs[d] + atomicAdd(&cur[d], 1);
        csr_src[pos] = s;
        csr_w[pos] = wn;
    }
}

// ---------------- pack kernels ----------------

// A[n][0:256]=bf16(x), A[n][256:512]=bf16(h)
__global__ void k_packA(const float* __restrict__ x, const float* __restrict__ h,
                        unsigned short* __restrict__ A, int n) {
    int t = blockIdx.x * blockDim.x + threadIdx.x;
    int node = t >> 6, q = t & 63;
    if (node >= n) return;
    floatx4 xv = *(const floatx4*)(x + (size_t)node * FDIM + q * 4);
    floatx4 hv = *(const floatx4*)(h + (size_t)node * FDIM + q * 4);
    ushort4 ox, oh;
    ox.x = f2bf(xv[0]); ox.y = f2bf(xv[1]); ox.z = f2bf(xv[2]); ox.w = f2bf(xv[3]);
    oh.x = f2bf(hv[0]); oh.y = f2bf(hv[1]); oh.z = f2bf(hv[2]); oh.w = f2bf(hv[3]);
    *(ushort4*)(A + (size_t)node * KDIM + q * 4) = ox;
    *(ushort4*)(A + (size_t)node * KDIM + FDIM + q * 4) = oh;
}

// Bt[j][r] = B[r][j], j=output col (gate g=j>>8, jj=j&255), r=k index
// B[r][j]: kb=r>>8 selects {W, theta0, theta1, theta2}, rr=r&255
__global__ void k_packBt(const float* __restrict__ W, const float* __restrict__ theta,
                         unsigned short* __restrict__ Bt) {
    int t = blockIdx.x * blockDim.x + threadIdx.x; // over 1024*1024
    int j = t >> 10, r = t & 1023;
    int g = j >> 8, jj = j & 255;
    int kb = r >> 8, rr = r & 255;
    float v;
    if (kb == 0) v = W[((size_t)(g * FDIM + rr)) * FDIM + jj];
    else         v = theta[((size_t)((g * 3 + (kb - 1)) * FDIM + rr)) * FDIM + jj];
    Bt[t] = f2bf(v);
}

// ---------------- sparse prop (CSR gather, wave per node) ----------------

// Tx1 = prop(h): gather bf16 h from A[:,256:512], write bf16 to A[:,512:768]
__global__ void k_prop1(unsigned short* __restrict__ A, const int* __restrict__ offs,
                        const int* __restrict__ csr_src, const float* __restrict__ csr_w, int n) {
    int wid = (blockIdx.x * blockDim.x + threadIdx.x) >> 6;
    int lane = threadIdx.x & 63;
    if (wid >= n) return;
    int beg = offs[wid], end = offs[wid + 1];
    float a0 = 0.f, a1 = 0.f, a2 = 0.f, a3 = 0.f;
    for (int j = beg; j < end; ++j) {
        int s = csr_src[j];
        float wv = csr_w[j];
        ushort4 v = *(const ushort4*)(A + (size_t)s * KDIM + FDIM + lane * 4);
        a0 += wv * bf2f(v.x); a1 += wv * bf2f(v.y);
        a2 += wv * bf2f(v.z); a3 += wv * bf2f(v.w);
    }
    ushort4 o;
    o.x = f2bf(a0); o.y = f2bf(a1); o.z = f2bf(a2); o.w = f2bf(a3);
    *(ushort4*)(A + (size_t)wid * KDIM + 2 * FDIM + lane * 4) = o;
}

// Tx2 = 2*prop(Tx1) - h: gather bf16 Tx1 from A[:,512:768], write bf16 to A[:,768:1024]
__global__ void k_prop2(unsigned short* __restrict__ A, const float* __restrict__ h,
                        const int* __restrict__ offs,
                        const int* __restrict__ csr_src, const float* __restrict__ csr_w, int n) {
    int wid = (blockIdx.x * blockDim.x + threadIdx.x) >> 6;
    int lane = threadIdx.x & 63;
    if (wid >= n) return;
    int beg = offs[wid], end = offs[wid + 1];
    float a0 = 0.f, a1 = 0.f, a2 = 0.f, a3 = 0.f;
    for (int j = beg; j < end; ++j) {
        int s = csr_src[j];
        float wv = csr_w[j];
        ushort4 v = *(const ushort4*)(A + (size_t)s * KDIM + 2 * FDIM + lane * 4);
        a0 += wv * bf2f(v.x); a1 += wv * bf2f(v.y);
        a2 += wv * bf2f(v.z); a3 += wv * bf2f(v.w);
    }
    floatx4 hv = *(const floatx4*)(h + (size_t)wid * FDIM + lane * 4);
    ushort4 o;
    o.x = f2bf(2.f * a0 - hv[0]); o.y = f2bf(2.f * a1 - hv[1]);
    o.z = f2bf(2.f * a2 - hv[2]); o.w = f2bf(2.f * a3 - hv[3]);
    *(ushort4*)(A + (size_t)wid * KDIM + 3 * FDIM + lane * 4) = o;
}

// ---------------- GEMM: Z[M,1024] = A[M,1024] @ B[1024,1024] (Bt = B^T) ----------------

__launch_bounds__(256)
__global__ void k_gemm(const unsigned short* __restrict__ A, const unsigned short* __restrict__ Bt,
                       float* __restrict__ Z, int M) {
    __shared__ unsigned short sA[128 * 32];
    __shared__ unsigned short sB[128 * 32];
    int tid = threadIdx.x;
    int lane = tid & 63;
    int w = tid >> 6;
    int mt = blockIdx.x >> 3;
    int nt = blockIdx.x & 7;
    int brow = mt * 128, bcol = nt * 128;
    int wr = (w >> 1) * 64, wc = (w & 1) * 64;
    int l15 = lane & 15, l4 = lane >> 4;

    floatx4 acc[4][4];
#pragma unroll
    for (int m = 0; m < 4; ++m)
#pragma unroll
        for (int nn = 0; nn < 4; ++nn)
            acc[m][nn] = (floatx4){0.f, 0.f, 0.f, 0.f};

    for (int kt = 0; kt < 32; ++kt) {
        int k0 = kt * 32;
#pragma unroll
        for (int p = 0; p < 2; ++p) {
            int cch = tid + p * 256;           // 0..511 chunks of 16B
            int row = cch >> 2, ks = (cch & 3) * 8;
            int grow = brow + row; if (grow >= M) grow = M - 1;
            const unsigned short* g = A + (size_t)grow * KDIM + k0 + ks;
            __builtin_amdgcn_global_load_lds((const GLOBAL_AS void*)g,
                                             (LDS_AS void*)(sA + cch * 8), 16, 0, 0);
        }
#pragma unroll
        for (int p = 0; p < 2; ++p) {
            int cch = tid + p * 256;
            int row = cch >> 2, ks = (cch & 3) * 8;
            const unsigned short* g = Bt + (size_t)(bcol + row) * KDIM + k0 + ks;
            __builtin_amdgcn_global_load_lds((const GLOBAL_AS void*)g,
                                             (LDS_AS void*)(sB + cch * 8), 16, 0, 0);
        }
        __syncthreads();

        short8 af[4], bfr[4];
#pragma unroll
        for (int m = 0; m < 4; ++m)
            af[m] = *(const short8*)(sA + (wr + m * 16 + l15) * 32 + l4 * 8);
#pragma unroll
        for (int nn = 0; nn < 4; ++nn)
            bfr[nn] = *(const short8*)(sB + (wc + nn * 16 + l15) * 32 + l4 * 8);
#pragma unroll
        for (int m = 0; m < 4; ++m)
#pragma unroll
            for (int nn = 0; nn < 4; ++nn)
                acc[m][nn] = __builtin_amdgcn_mfma_f32_16x16x32_bf16(af[m], bfr[nn], acc[m][nn], 0, 0, 0);
        __syncthreads();
    }

#pragma unroll
    for (int m = 0; m < 4; ++m) {
        int r0 = brow + wr + m * 16 + l4 * 4;
#pragma unroll
        for (int nn = 0; nn < 4; ++nn) {
            int cc = bcol + wc + nn * 16 + l15;
#pragma unroll
            for (int j = 0; j < 4; ++j) {
                int r = r0 + j;
                if (r < M) Z[(size_t)r * KDIM + cc] = acc[m][nn][j];
            }
        }
    }
}

// ---------------- fused LSTM epilogue + classifier ----------------

__global__ void k_epilogue(const float* __restrict__ Z, const float* __restrict__ c,
                           const float* __restrict__ b_conv, const float* __restrict__ b,
                           const float* __restrict__ w_c, const float* __restrict__ Wcls,
                           const float* __restrict__ bcls,
                           float* __restrict__ out_cls, float* __restrict__ out_h,
                           float* __restrict__ out_c, int n) {
    int wid = (blockIdx.x * blockDim.x + threadIdx.x) >> 6;
    int lane = threadIdx.x & 63;
    if (wid >= n) return;
    int fb = lane * 4;
    const float* zr = Z + (size_t)wid * KDIM + fb;
    floatx4 zi = *(const floatx4*)(zr);
    floatx4 zf = *(const floatx4*)(zr + 256);
    floatx4 zt = *(const floatx4*)(zr + 512);
    floatx4 zo = *(const floatx4*)(zr + 768);
    floatx4 cv = *(const floatx4*)(c + (size_t)wid * FDIM + fb);
    floatx4 wci = *(const floatx4*)(w_c + fb);
    floatx4 wcf = *(const floatx4*)(w_c + FDIM + fb);
    floatx4 wco = *(const floatx4*)(w_c + 2 * FDIM + fb);
    floatx4 b0 = *(const floatx4*)(b + fb);
    floatx4 b1 = *(const floatx4*)(b + FDIM + fb);
    floatx4 b2 = *(const floatx4*)(b + 2 * FDIM + fb);
    floatx4 b3 = *(const floatx4*)(b + 3 * FDIM + fb);
    floatx4 bc0 = *(const floatx4*)(b_conv + fb);
    floatx4 bc1 = *(const floatx4*)(b_conv + FDIM + fb);
    floatx4 bc2 = *(const floatx4*)(b_conv + 2 * FDIM + fb);
    floatx4 bc3 = *(const floatx4*)(b_conv + 3 * FDIM + fb);
    floatx4 wl = *(const floatx4*)(Wcls + fb);

    floatx4 hn, cn;
    float dot = 0.f;
#pragma unroll
    for (int j = 0; j < 4; ++j) {
        float iv = sig(zi[j] + bc0[j] + wci[j] * cv[j] + b0[j]);
        float fv = sig(zf[j] + bc1[j] + wcf[j] * cv[j] + b1[j]);
        float tv = tanhf(zt[j] + bc2[j] + b2[j]);
        float cnj = fv * cv[j] + iv * tv;
        float ov = sig(zo[j] + bc3[j] + wco[j] * cnj + b3[j]);
        float hj = ov * tanhf(cnj);
        cn[j] = cnj;
        hn[j] = hj;
        dot += fmaxf(hj, 0.f) * wl[j];
    }
    *(floatx4*)(out_h + (size_t)wid * FDIM + fb) = hn;
    *(floatx4*)(out_c + (size_t)wid * FDIM + fb) = cn;
#pragma unroll
    for (int s = 32; s; s >>= 1) dot += __shfl_down(dot, s);
    if (lane == 0) out_cls[wid] = dot + bcls[0];
}

// ---------------- launcher ----------------

extern "C" void kernel_launch(void* const* d_in, const int* in_sizes, int n_in,
                              void* d_out, int out_size, void* d_ws, size_t ws_size,
                              hipStream_t stream) {
    const float* x      = (const float*)d_in[0];
    const int*   eidx   = (const int*)d_in[1];
    const float* ew     = (const float*)d_in[2];
    const float* h      = (const float*)d_in[3];
    const float* c      = (const float*)d_in[4];
    const float* W      = (const float*)d_in[5];
    const float* theta  = (const float*)d_in[6];
    const float* b_conv = (const float*)d_in[7];
    const float* b      = (const float*)d_in[8];
    const float* w_c    = (const float*)d_in[9];
    const float* Wcls   = (const float*)d_in[10];
    const float* bcls   = (const float*)d_in[11];

    const int N = in_sizes[0] / FDIM;
    const int E = in_sizes[2];
    const int* src = eidx;
    const int* dst = eidx + E;

    char* ws = (char*)d_ws;
    size_t off = 0;
    auto alloc = [&](size_t bytes) -> void* {
        void* p = ws + off;
        off += (bytes + 255) & ~(size_t)255;
        return p;
    };
    unsigned short* A   = (unsigned short*)alloc((size_t)N * KDIM * 2);
    unsigned short* Bt  = (unsigned short*)alloc((size_t)KDIM * KDIM * 2);
    float* Z            = (float*)alloc((size_t)N * KDIM * 4);
    float* deg          = (float*)alloc((size_t)N * 4);
    float* dis          = (float*)alloc((size_t)N * 4);
    int*   cnt          = (int*)alloc((size_t)N * 4);
    int*   offs         = (int*)alloc((size_t)(N + 1) * 4);
    int*   cur          = (int*)alloc((size_t)N * 4);
    int*   csr_src      = (int*)alloc((size_t)E * 4);
    float* csr_w        = (float*)alloc((size_t)E * 4);
    (void)ws_size; (void)n_in; (void)out_size;

    float* out_cls = (float*)d_out;
    float* out_h   = out_cls + N;
    float* out_c   = out_h + (size_t)N * FDIM;

    k_init<<<(N + 255) / 256, 256, 0, stream>>>(deg, cnt, cur, N);
    k_degcnt<<<(E + 255) / 256, 256, 0, stream>>>(src, dst, ew, deg, cnt, E);
    k_dis<<<(N + 255) / 256, 256, 0, stream>>>(deg, dis, N);
    k_scan<<<1, 1024, 0, stream>>>(cnt, offs, N);
    k_scatter<<<(E + 255) / 256, 256, 0, stream>>>(src, dst, ew, dis, offs, cur, csr_src, csr_w, E);
    k_packA<<<(N * 64 + 255) / 256, 256, 0, stream>>>(x, h, A, N);
    k_packBt<<<(KDIM * KDIM + 255) / 256, 256, 0, stream>>>(W, theta, Bt);
    k_prop1<<<(N * 64 + 255) / 256, 256, 0, stream>>>(A, offs, csr_src, csr_w, N);
    k_prop2<<<(N * 64 + 255) / 256, 256, 0, stream>>>(A, h, offs, csr_src, csr_w, N);
    int mtiles = (N + 127) / 128;
    k_gemm<<<mtiles * 8, 256, 0, stream>>>(A, Bt, Z, N);
    k_epilogue<<<(N * 64 + 255) / 256, 256, 0, stream>>>(Z, c, b_conv, b, w_c, Wcls, bcls,
                                                         out_cls, out_h, out_c, N);
}

// Round 2
// 255.702 us; speedup vs baseline: 1.1943x; 1.1943x over previous
//
#include <hip/hip_runtime.h>
#include <stdint.h>

#define FDIM 256
#define KDIM 1024   // 4*F : [x | h | Tx1 | Tx2]

typedef __attribute__((ext_vector_type(8))) short short8;
typedef __attribute__((ext_vector_type(4))) float floatx4;

#define GLOBAL_AS __attribute__((address_space(1)))
#define LDS_AS    __attribute__((address_space(3)))

static __device__ __forceinline__ unsigned short f2bf(float f) {
    unsigned int u = __float_as_uint(f);
    unsigned int r = (u + 0x7FFFu + ((u >> 16) & 1u)) >> 16;
    return (unsigned short)r;
}
static __device__ __forceinline__ float bf2f(unsigned short s) {
    return __uint_as_float(((unsigned int)s) << 16);
}
static __device__ __forceinline__ float sig(float x) {
    return 1.f / (1.f + __expf(-x));
}

// ---------------- setup kernels ----------------

__global__ void k_init(float* deg, int* cnt, int* cur, int n) {
    int i = blockIdx.x * blockDim.x + threadIdx.x;
    if (i < n) { deg[i] = 0.f; cnt[i] = 0; cur[i] = 0; }
}

__global__ void k_degcnt(const int* __restrict__ src, const int* __restrict__ dst,
                         const float* __restrict__ ew, float* deg, int* cnt, int e) {
    int i = blockIdx.x * blockDim.x + threadIdx.x;
    if (i < e) {
        atomicAdd(&deg[src[i]], ew[i]);
        atomicAdd(&cnt[dst[i]], 1);
    }
}

__global__ void k_dis(const float* __restrict__ deg, float* __restrict__ dis, int n) {
    int i = blockIdx.x * blockDim.x + threadIdx.x;
    if (i < n) {
        float d = deg[i];
        dis[i] = d > 0.f ? rsqrtf(fmaxf(d, 1e-12f)) : 0.f;
    }
}

// single-block scan, shfl-based: offs[0]=0, offs[i+1]=sum(cnt[0..i])
__launch_bounds__(1024)
__global__ void k_scan(const int* __restrict__ cnt, int* __restrict__ offs, int n) {
    __shared__ int wsum[16];
    int lane = threadIdx.x & 63;
    int wid = threadIdx.x >> 6;
    int base = 0;
    for (int start = 0; start < n; start += 1024) {
        int i = start + (int)threadIdx.x;
        int x = (i < n) ? cnt[i] : 0;
        // per-wave inclusive scan
#pragma unroll
        for (int s = 1; s < 64; s <<= 1) {
            int t = __shfl_up(x, s);
            if (lane >= s) x += t;
        }
        if (lane == 63) wsum[wid] = x;
        __syncthreads();
        if (wid == 0) {
            int y = (lane < 16) ? wsum[lane] : 0;
#pragma unroll
            for (int s = 1; s < 16; s <<= 1) {
                int t = __shfl_up(y, s);
                if (lane >= s) y += t;
            }
            if (lane < 16) wsum[lane] = y;
        }
        __syncthreads();
        int wbase = (wid > 0) ? wsum[wid - 1] : 0;
        int total = wsum[15];
        if (i < n) offs[i + 1] = base + wbase + x;
        base += total;
        __syncthreads();
    }
    if (threadIdx.x == 0) offs[0] = 0;
}

__global__ void k_scatter(const int* __restrict__ src, const int* __restrict__ dst,
                          const float* __restrict__ ew, const float* __restrict__ dis,
                          const int* __restrict__ offs, int* cur,
                          int* __restrict__ csr_src, float* __restrict__ csr_w, int e) {
    int i = blockIdx.x * blockDim.x + threadIdx.x;
    if (i < e) {
        int s = src[i], d = dst[i];
        float wn = -dis[s] * ew[i] * dis[d];
        int pos = offs[d] + atomicAdd(&cur[d], 1);
        csr_src[pos] = s;
        csr_w[pos] = wn;
    }
}

// ---------------- pack kernels ----------------

// A[n][0:256]=bf16(x), A[n][256:512]=bf16(h)
__global__ void k_packA(const float* __restrict__ x, const float* __restrict__ h,
                        unsigned short* __restrict__ A, int n) {
    int t = blockIdx.x * blockDim.x + threadIdx.x;
    int node = t >> 6, q = t & 63;
    if (node >= n) return;
    floatx4 xv = *(const floatx4*)(x + (size_t)node * FDIM + q * 4);
    floatx4 hv = *(const floatx4*)(h + (size_t)node * FDIM + q * 4);
    ushort4 ox, oh;
    ox.x = f2bf(xv[0]); ox.y = f2bf(xv[1]); ox.z = f2bf(xv[2]); ox.w = f2bf(xv[3]);
    oh.x = f2bf(hv[0]); oh.y = f2bf(hv[1]); oh.z = f2bf(hv[2]); oh.w = f2bf(hv[3]);
    *(ushort4*)(A + (size_t)node * KDIM + q * 4) = ox;
    *(ushort4*)(A + (size_t)node * KDIM + FDIM + q * 4) = oh;
}

// Gate-interleaved packed B^T.
// packed col p: group=p>>6, gate=(p>>4)&3, feat=(group<<4)|(p&15)
// row r: kb=r>>8 selects {W, theta0, theta1, theta2}, rr=r&255
// Bt[p*1024 + r] = B[r][p]
__global__ void k_packBt(const float* __restrict__ W, const float* __restrict__ theta,
                         unsigned short* __restrict__ Bt) {
    int t = blockIdx.x * blockDim.x + threadIdx.x; // over 1024*1024
    int p = t >> 10, r = t & 1023;
    int group = p >> 6, gate = (p >> 4) & 3;
    int feat = (group << 4) | (p & 15);
    int kb = r >> 8, rr = r & 255;
    float v;
    if (kb == 0) v = W[((size_t)(gate * FDIM + rr)) * FDIM + feat];
    else         v = theta[((size_t)((gate * 3 + (kb - 1)) * FDIM + rr)) * FDIM + feat];
    Bt[t] = f2bf(v);
}

// ---------------- sparse prop (CSR gather, wave per node) ----------------

// Tx1 = prop(h): gather bf16 h from A[:,256:512], write bf16 to A[:,512:768]
__global__ void k_prop1(unsigned short* __restrict__ A, const int* __restrict__ offs,
                        const int* __restrict__ csr_src, const float* __restrict__ csr_w, int n) {
    int wid = (blockIdx.x * blockDim.x + threadIdx.x) >> 6;
    int lane = threadIdx.x & 63;
    if (wid >= n) return;
    int beg = offs[wid], end = offs[wid + 1];
    float a0 = 0.f, a1 = 0.f, a2 = 0.f, a3 = 0.f;
    for (int j = beg; j < end; ++j) {
        int s = csr_src[j];
        float wv = csr_w[j];
        ushort4 v = *(const ushort4*)(A + (size_t)s * KDIM + FDIM + lane * 4);
        a0 += wv * bf2f(v.x); a1 += wv * bf2f(v.y);
        a2 += wv * bf2f(v.z); a3 += wv * bf2f(v.w);
    }
    ushort4 o;
    o.x = f2bf(a0); o.y = f2bf(a1); o.z = f2bf(a2); o.w = f2bf(a3);
    *(ushort4*)(A + (size_t)wid * KDIM + 2 * FDIM + lane * 4) = o;
}

// Tx2 = 2*prop(Tx1) - h: gather bf16 Tx1 from A[:,512:768], write bf16 to A[:,768:1024]
__global__ void k_prop2(unsigned short* __restrict__ A, const float* __restrict__ h,
                        const int* __restrict__ offs,
                        const int* __restrict__ csr_src, const float* __restrict__ csr_w, int n) {
    int wid = (blockIdx.x * blockDim.x + threadIdx.x) >> 6;
    int lane = threadIdx.x & 63;
    if (wid >= n) return;
    int beg = offs[wid], end = offs[wid + 1];
    float a0 = 0.f, a1 = 0.f, a2 = 0.f, a3 = 0.f;
    for (int j = beg; j < end; ++j) {
        int s = csr_src[j];
        float wv = csr_w[j];
        ushort4 v = *(const ushort4*)(A + (size_t)s * KDIM + 2 * FDIM + lane * 4);
        a0 += wv * bf2f(v.x); a1 += wv * bf2f(v.y);
        a2 += wv * bf2f(v.z); a3 += wv * bf2f(v.w);
    }
    floatx4 hv = *(const floatx4*)(h + (size_t)wid * FDIM + lane * 4);
    ushort4 o;
    o.x = f2bf(2.f * a0 - hv[0]); o.y = f2bf(2.f * a1 - hv[1]);
    o.z = f2bf(2.f * a2 - hv[2]); o.w = f2bf(2.f * a3 - hv[3]);
    *(ushort4*)(A + (size_t)wid * KDIM + 3 * FDIM + lane * 4) = o;
}

// ---------------- GEMM + fused LSTM epilogue ----------------
// C[M,1024packed] = A[M,1024] @ Bpacked, epilogue applied in-register.
// Per-wave N-span of 64 packed cols = one feature-group: 4 fragments = 4 gates,
// same 16 feats. acc[m][g][j] = gate-g preactivation at (node, feat).

__launch_bounds__(256, 3)
__global__ void k_gemm(const unsigned short* __restrict__ A, const unsigned short* __restrict__ Bt,
                       const float* __restrict__ c, const float* __restrict__ b_conv,
                       const float* __restrict__ b, const float* __restrict__ w_c,
                       const float* __restrict__ Wcls,
                       float* __restrict__ out_h, float* __restrict__ out_c,
                       float* __restrict__ cls_part, int M, int mtiles) {
    __shared__ unsigned short sA[128 * 32];
    __shared__ unsigned short sB[128 * 32];
    int tid = threadIdx.x;
    int lane = tid & 63;
    int w = tid >> 6;
    // XCD-aware swizzle: 8 consecutive nt-blocks (sharing one A panel) -> same XCD
    int nb = mtiles * 8;
    int bid = blockIdx.x;
    int wg = (bid & 7) * (nb >> 3) + (bid >> 3);
    int mt = wg >> 3;
    int nt = wg & 7;
    int brow = mt * 128, bcol = nt * 128;
    int wr = (w >> 1) * 64, wc = (w & 1) * 64;
    int l15 = lane & 15, l4 = lane >> 4;

    floatx4 acc[4][4];
#pragma unroll
    for (int m = 0; m < 4; ++m)
#pragma unroll
        for (int g = 0; g < 4; ++g)
            acc[m][g] = (floatx4){0.f, 0.f, 0.f, 0.f};

    for (int kt = 0; kt < 32; ++kt) {
        int k0 = kt * 32;
#pragma unroll
        for (int p = 0; p < 2; ++p) {
            int cch = tid + p * 256;           // 0..511 chunks of 16B
            int row = cch >> 2, ks = (cch & 3) * 8;
            int grow = brow + row; if (grow >= M) grow = M - 1;
            const unsigned short* g = A + (size_t)grow * KDIM + k0 + ks;
            __builtin_amdgcn_global_load_lds((const GLOBAL_AS void*)g,
                                             (LDS_AS void*)(sA + cch * 8), 16, 0, 0);
        }
#pragma unroll
        for (int p = 0; p < 2; ++p) {
            int cch = tid + p * 256;
            int row = cch >> 2, ks = (cch & 3) * 8;
            const unsigned short* g = Bt + (size_t)(bcol + row) * KDIM + k0 + ks;
            __builtin_amdgcn_global_load_lds((const GLOBAL_AS void*)g,
                                             (LDS_AS void*)(sB + cch * 8), 16, 0, 0);
        }
        __syncthreads();

        short8 af[4], bfr[4];
#pragma unroll
        for (int m = 0; m < 4; ++m)
            af[m] = *(const short8*)(sA + (wr + m * 16 + l15) * 32 + l4 * 8);
#pragma unroll
        for (int g = 0; g < 4; ++g)
            bfr[g] = *(const short8*)(sB + (wc + g * 16 + l15) * 32 + l4 * 8);
#pragma unroll
        for (int m = 0; m < 4; ++m)
#pragma unroll
            for (int g = 0; g < 4; ++g)
                acc[m][g] = __builtin_amdgcn_mfma_f32_16x16x32_bf16(af[m], bfr[g], acc[m][g], 0, 0, 0);
        __syncthreads();
    }

    // fused epilogue: this wave owns feature-group `group` for its 128 rows slice
    int group = (bcol + wc) >> 6;          // 0..15
    int feat = (group << 4) | l15;         // 0..255
    float bc0 = b_conv[feat], bc1 = b_conv[FDIM + feat];
    float bc2 = b_conv[2 * FDIM + feat], bc3 = b_conv[3 * FDIM + feat];
    float bb0 = b[feat], bb1 = b[FDIM + feat];
    float bb2 = b[2 * FDIM + feat], bb3 = b[3 * FDIM + feat];
    float wci = w_c[feat], wcf = w_c[FDIM + feat], wco = w_c[2 * FDIM + feat];
    float wcl = Wcls[feat];

#pragma unroll
    for (int m = 0; m < 4; ++m) {
#pragma unroll
        for (int j = 0; j < 4; ++j) {
            int node = brow + wr + m * 16 + l4 * 4 + j;
            bool ok = node < M;
            int nidx = ok ? node : (M - 1);
            float cv = c[(size_t)nidx * FDIM + feat];
            float iv = sig(acc[m][0][j] + bc0 + wci * cv + bb0);
            float fv = sig(acc[m][1][j] + bc1 + wcf * cv + bb1);
            float tv = tanhf(acc[m][2][j] + bc2 + bb2);
            float cn = fv * cv + iv * tv;
            float ov = sig(acc[m][3][j] + bc3 + wco * cn + bb3);
            float hn = ov * tanhf(cn);
            if (ok) {
                out_h[(size_t)node * FDIM + feat] = hn;
                out_c[(size_t)node * FDIM + feat] = cn;
            }
            float pcls = fmaxf(hn, 0.f) * wcl;
#pragma unroll
            for (int s = 1; s < 16; s <<= 1) pcls += __shfl_xor(pcls, s);
            if (ok && l15 == 0) cls_part[(size_t)node * 16 + group] = pcls;
        }
    }
}

// classifier partial reduce: out_cls[i] = sum_g cls_part[i][g] + b_cls
__global__ void k_cls(const float* __restrict__ cls_part, const float* __restrict__ bcls,
                      float* __restrict__ out_cls, int n) {
    int i = blockIdx.x * blockDim.x + threadIdx.x;
    if (i >= n) return;
    const floatx4* p = (const floatx4*)(cls_part + (size_t)i * 16);
    floatx4 v0 = p[0], v1 = p[1], v2 = p[2], v3 = p[3];
    float s = v0[0] + v0[1] + v0[2] + v0[3] + v1[0] + v1[1] + v1[2] + v1[3]
            + v2[0] + v2[1] + v2[2] + v2[3] + v3[0] + v3[1] + v3[2] + v3[3];
    out_cls[i] = s + bcls[0];
}

// ---------------- launcher ----------------

extern "C" void kernel_launch(void* const* d_in, const int* in_sizes, int n_in,
                              void* d_out, int out_size, void* d_ws, size_t ws_size,
                              hipStream_t stream) {
    const float* x      = (const float*)d_in[0];
    const int*   eidx   = (const int*)d_in[1];
    const float* ew     = (const float*)d_in[2];
    const float* h      = (const float*)d_in[3];
    const float* c      = (const float*)d_in[4];
    const float* W      = (const float*)d_in[5];
    const float* theta  = (const float*)d_in[6];
    const float* b_conv = (const float*)d_in[7];
    const float* b      = (const float*)d_in[8];
    const float* w_c    = (const float*)d_in[9];
    const float* Wcls   = (const float*)d_in[10];
    const float* bcls   = (const float*)d_in[11];

    const int N = in_sizes[0] / FDIM;
    const int E = in_sizes[2];
    const int* src = eidx;
    const int* dst = eidx + E;

    char* ws = (char*)d_ws;
    size_t off = 0;
    auto alloc = [&](size_t bytes) -> void* {
        void* p = ws + off;
        off += (bytes + 255) & ~(size_t)255;
        return p;
    };
    unsigned short* A   = (unsigned short*)alloc((size_t)N * KDIM * 2);
    unsigned short* Bt  = (unsigned short*)alloc((size_t)KDIM * KDIM * 2);
    float* cls_part     = (float*)alloc((size_t)N * 16 * 4);
    float* deg          = (float*)alloc((size_t)N * 4);
    float* dis          = (float*)alloc((size_t)N * 4);
    int*   cnt          = (int*)alloc((size_t)N * 4);
    int*   offs         = (int*)alloc((size_t)(N + 1) * 4);
    int*   cur          = (int*)alloc((size_t)N * 4);
    int*   csr_src      = (int*)alloc((size_t)E * 4);
    float* csr_w        = (float*)alloc((size_t)E * 4);
    (void)ws_size; (void)n_in; (void)out_size;

    float* out_cls = (float*)d_out;
    float* out_h   = out_cls + N;
    float* out_c   = out_h + (size_t)N * FDIM;

    k_init<<<(N + 255) / 256, 256, 0, stream>>>(deg, cnt, cur, N);
    k_degcnt<<<(E + 255) / 256, 256, 0, stream>>>(src, dst, ew, deg, cnt, E);
    k_dis<<<(N + 255) / 256, 256, 0, stream>>>(deg, dis, N);
    k_scan<<<1, 1024, 0, stream>>>(cnt, offs, N);
    k_scatter<<<(E + 255) / 256, 256, 0, stream>>>(src, dst, ew, dis, offs, cur, csr_src, csr_w, E);
    k_packA<<<(N * 64 + 255) / 256, 256, 0, stream>>>(x, h, A, N);
    k_packBt<<<(KDIM * KDIM + 255) / 256, 256, 0, stream>>>(W, theta, Bt);
    k_prop1<<<(N * 64 + 255) / 256, 256, 0, stream>>>(A, offs, csr_src, csr_w, N);
    k_prop2<<<(N * 64 + 255) / 256, 256, 0, stream>>>(A, h, offs, csr_src, csr_w, N);
    int mtiles = (N + 127) / 128;
    k_gemm<<<mtiles * 8, 256, 0, stream>>>(A, Bt, c, b_conv, b, w_c, Wcls,
                                           out_h, out_c, cls_part, N, mtiles);
    k_cls<<<(N + 255) / 256, 256, 0, stream>>>(cls_part, bcls, out_cls, N);
}

// Round 3
// 200.599 us; speedup vs baseline: 1.5224x; 1.2747x over previous
//
#include <hip/hip_runtime.h>
#include <stdint.h>

#define FDIM 256
#define KDIM 1024   // 4*F : [x | h | Tx1 | Tx2]

typedef __attribute__((ext_vector_type(8))) short short8;
typedef __attribute__((ext_vector_type(4))) float floatx4;

#define GLOBAL_AS __attribute__((address_space(1)))
#define LDS_AS    __attribute__((address_space(3)))

static __device__ __forceinline__ unsigned short f2bf(float f) {
    unsigned int u = __float_as_uint(f);
    unsigned int r = (u + 0x7FFFu + ((u >> 16) & 1u)) >> 16;
    return (unsigned short)r;
}
static __device__ __forceinline__ float bf2f(unsigned short s) {
    return __uint_as_float(((unsigned int)s) << 16);
}
static __device__ __forceinline__ float sig(float x) {
    return 1.f / (1.f + __expf(-x));
}

// ---------------- setup kernels ----------------

__global__ void k_degcnt(const int* __restrict__ src, const int* __restrict__ dst,
                         const float* __restrict__ ew, float* deg, int* cnt, int e) {
    int i = blockIdx.x * blockDim.x + threadIdx.x;
    if (i < e) {
        atomicAdd(&deg[src[i]], ew[i]);
        atomicAdd(&cnt[dst[i]], 1);
    }
}

__global__ void k_dis(const float* __restrict__ deg, float* __restrict__ dis, int n) {
    int i = blockIdx.x * blockDim.x + threadIdx.x;
    if (i < n) {
        float d = deg[i];
        dis[i] = d > 0.f ? rsqrtf(fmaxf(d, 1e-12f)) : 0.f;
    }
}

// hierarchical scan, stage 1: per-1024-block inclusive scan -> offs[i+1], block total -> part[b]
__launch_bounds__(1024)
__global__ void k_scan1(const int* __restrict__ cnt, int* __restrict__ offs,
                        int* __restrict__ part, int n) {
    __shared__ int wsum[16];
    int b = blockIdx.x;
    int i = b * 1024 + (int)threadIdx.x;
    int lane = threadIdx.x & 63;
    int wid = threadIdx.x >> 6;
    int x = (i < n) ? cnt[i] : 0;
#pragma unroll
    for (int s = 1; s < 64; s <<= 1) {
        int t = __shfl_up(x, s);
        if (lane >= s) x += t;
    }
    if (lane == 63) wsum[wid] = x;
    __syncthreads();
    if (wid == 0) {
        int y = (lane < 16) ? wsum[lane] : 0;
#pragma unroll
        for (int s = 1; s < 16; s <<= 1) {
            int t = __shfl_up(y, s);
            if (lane >= s) y += t;
        }
        if (lane < 16) wsum[lane] = y;
    }
    __syncthreads();
    int wbase = (wid > 0) ? wsum[wid - 1] : 0;
    if (i < n) offs[i + 1] = wbase + x;
    if (threadIdx.x == 1023) part[b] = wsum[15];
}

// stage 2: add exclusive prefix of part[] to each block's region (nb <= 64)
__launch_bounds__(1024)
__global__ void k_scan2(int* __restrict__ offs, const int* __restrict__ part, int n) {
    __shared__ int sprefix;
    int b = blockIdx.x;
    if (threadIdx.x < 64) {
        int p = ((int)threadIdx.x < b) ? part[threadIdx.x] : 0;
#pragma unroll
        for (int s = 32; s; s >>= 1) p += __shfl_down(p, s);
        if (threadIdx.x == 0) sprefix = p;
    }
    __syncthreads();
    int i = b * 1024 + (int)threadIdx.x;
    if (i < n) offs[i + 1] += sprefix;
    if (b == 0 && threadIdx.x == 0) offs[0] = 0;
}

__global__ void k_scatter(const int* __restrict__ src, const int* __restrict__ dst,
                          const float* __restrict__ ew, const float* __restrict__ dis,
                          const int* __restrict__ offs, int* cur,
                          int* __restrict__ csr_src, float* __restrict__ csr_w, int e) {
    int i = blockIdx.x * blockDim.x + threadIdx.x;
    if (i < e) {
        int s = src[i], d = dst[i];
        float wn = -dis[s] * ew[i] * dis[d];
        int pos = offs[d] + atomicAdd(&cur[d], 1);
        csr_src[pos] = s;
        csr_w[pos] = wn;
    }
}

// ---------------- pack kernels ----------------

// A[n][0:256]=bf16(x), A[n][256:512]=bf16(h)
__global__ void k_packA(const float* __restrict__ x, const float* __restrict__ h,
                        unsigned short* __restrict__ A, int n) {
    int t = blockIdx.x * blockDim.x + threadIdx.x;
    int node = t >> 6, q = t & 63;
    if (node >= n) return;
    floatx4 xv = *(const floatx4*)(x + (size_t)node * FDIM + q * 4);
    floatx4 hv = *(const floatx4*)(h + (size_t)node * FDIM + q * 4);
    ushort4 ox, oh;
    ox.x = f2bf(xv[0]); ox.y = f2bf(xv[1]); ox.z = f2bf(xv[2]); ox.w = f2bf(xv[3]);
    oh.x = f2bf(hv[0]); oh.y = f2bf(hv[1]); oh.z = f2bf(hv[2]); oh.w = f2bf(hv[3]);
    *(ushort4*)(A + (size_t)node * KDIM + q * 4) = ox;
    *(ushort4*)(A + (size_t)node * KDIM + FDIM + q * 4) = oh;
}

// Gate-interleaved packed B^T.
// packed col p: group=p>>6, gate=(p>>4)&3, feat=(group<<4)|(p&15)
// row r: kb=r>>8 selects {W, theta0, theta1, theta2}, rr=r&255
__global__ void k_packBt(const float* __restrict__ W, const float* __restrict__ theta,
                         unsigned short* __restrict__ Bt) {
    int t = blockIdx.x * blockDim.x + threadIdx.x; // over 1024*1024
    int p = t >> 10, r = t & 1023;
    int group = p >> 6, gate = (p >> 4) & 3;
    int feat = (group << 4) | (p & 15);
    int kb = r >> 8, rr = r & 255;
    float v;
    if (kb == 0) v = W[((size_t)(gate * FDIM + rr)) * FDIM + feat];
    else         v = theta[((size_t)((gate * 3 + (kb - 1)) * FDIM + rr)) * FDIM + feat];
    Bt[t] = f2bf(v);
}

// ---------------- sparse prop (CSR gather, wave per node, 2 half-waves x 2 unroll) ----------------

// Tx1 = prop(h): gather bf16 h from A[:,256:512], write bf16 to A[:,512:768]
__launch_bounds__(256)
__global__ void k_prop1(unsigned short* __restrict__ A, const int* __restrict__ offs,
                        const int* __restrict__ csr_src, const float* __restrict__ csr_w, int n) {
    int wid = (blockIdx.x * blockDim.x + threadIdx.x) >> 6;
    int lane = threadIdx.x & 63;
    if (wid >= n) return;
    int half = lane >> 5, l = lane & 31;
    int beg = offs[wid], end = offs[wid + 1];
    float a[8] = {0.f, 0.f, 0.f, 0.f, 0.f, 0.f, 0.f, 0.f};
    int j = beg + half;
    for (; j + 2 < end; j += 4) {
        int s0 = csr_src[j], s1 = csr_src[j + 2];
        float w0 = csr_w[j], w1 = csr_w[j + 2];
        short8 v0 = *(const short8*)(A + (size_t)s0 * KDIM + FDIM + l * 8);
        short8 v1 = *(const short8*)(A + (size_t)s1 * KDIM + FDIM + l * 8);
#pragma unroll
        for (int k = 0; k < 8; ++k)
            a[k] += w0 * bf2f((unsigned short)v0[k]) + w1 * bf2f((unsigned short)v1[k]);
    }
    if (j < end) {
        int s0 = csr_src[j];
        float w0 = csr_w[j];
        short8 v0 = *(const short8*)(A + (size_t)s0 * KDIM + FDIM + l * 8);
#pragma unroll
        for (int k = 0; k < 8; ++k) a[k] += w0 * bf2f((unsigned short)v0[k]);
    }
#pragma unroll
    for (int k = 0; k < 8; ++k) a[k] += __shfl_xor(a[k], 32);
    if (half == 0) {
        short8 o;
#pragma unroll
        for (int k = 0; k < 8; ++k) o[k] = (short)f2bf(a[k]);
        *(short8*)(A + (size_t)wid * KDIM + 2 * FDIM + l * 8) = o;
    }
}

// Tx2 = 2*prop(Tx1) - h
__launch_bounds__(256)
__global__ void k_prop2(unsigned short* __restrict__ A, const float* __restrict__ h,
                        const int* __restrict__ offs,
                        const int* __restrict__ csr_src, const float* __restrict__ csr_w, int n) {
    int wid = (blockIdx.x * blockDim.x + threadIdx.x) >> 6;
    int lane = threadIdx.x & 63;
    if (wid >= n) return;
    int half = lane >> 5, l = lane & 31;
    int beg = offs[wid], end = offs[wid + 1];
    float a[8] = {0.f, 0.f, 0.f, 0.f, 0.f, 0.f, 0.f, 0.f};
    int j = beg + half;
    for (; j + 2 < end; j += 4) {
        int s0 = csr_src[j], s1 = csr_src[j + 2];
        float w0 = csr_w[j], w1 = csr_w[j + 2];
        short8 v0 = *(const short8*)(A + (size_t)s0 * KDIM + 2 * FDIM + l * 8);
        short8 v1 = *(const short8*)(A + (size_t)s1 * KDIM + 2 * FDIM + l * 8);
#pragma unroll
        for (int k = 0; k < 8; ++k)
            a[k] += w0 * bf2f((unsigned short)v0[k]) + w1 * bf2f((unsigned short)v1[k]);
    }
    if (j < end) {
        int s0 = csr_src[j];
        float w0 = csr_w[j];
        short8 v0 = *(const short8*)(A + (size_t)s0 * KDIM + 2 * FDIM + l * 8);
#pragma unroll
        for (int k = 0; k < 8; ++k) a[k] += w0 * bf2f((unsigned short)v0[k]);
    }
#pragma unroll
    for (int k = 0; k < 8; ++k) a[k] += __shfl_xor(a[k], 32);
    if (half == 0) {
        floatx4 hv0 = *(const floatx4*)(h + (size_t)wid * FDIM + l * 8);
        floatx4 hv1 = *(const floatx4*)(h + (size_t)wid * FDIM + l * 8 + 4);
        short8 o;
#pragma unroll
        for (int k = 0; k < 4; ++k) o[k] = (short)f2bf(2.f * a[k] - hv0[k]);
#pragma unroll
        for (int k = 0; k < 4; ++k) o[4 + k] = (short)f2bf(2.f * a[4 + k] - hv1[k]);
        *(short8*)(A + (size_t)wid * KDIM + 3 * FDIM + l * 8) = o;
    }
}

// ---------------- GEMM + fused LSTM epilogue ----------------
// BK=64, XOR-swizzled LDS (linear dest + inverse-swizzled global source, rule #21).
// Per-wave N-span of 64 packed cols = one feature-group: 4 fragments = 4 gates.

__launch_bounds__(256, 3)
__global__ void k_gemm(const unsigned short* __restrict__ A, const unsigned short* __restrict__ Bt,
                       const float* __restrict__ c, const float* __restrict__ b_conv,
                       const float* __restrict__ b, const float* __restrict__ w_c,
                       const float* __restrict__ Wcls,
                       float* __restrict__ out_h, float* __restrict__ out_c,
                       float* __restrict__ cls_part, int M, int mtiles) {
    __shared__ unsigned short sA[128 * 64];
    __shared__ unsigned short sB[128 * 64];
    int tid = threadIdx.x;
    int lane = tid & 63;
    int w = tid >> 6;
    // XCD-aware swizzle: 8 consecutive nt-blocks (one A panel) land on one XCD chunk
    int nb = mtiles * 8;
    int bid = blockIdx.x;
    int wg = (bid & 7) * (nb >> 3) + (bid >> 3);
    int mt = wg >> 3;
    int nt = wg & 7;
    int brow = mt * 128, bcol = nt * 128;
    int wr = (w >> 1) * 64, wc = (w & 1) * 64;
    int l15 = lane & 15, l4 = lane >> 4;

    floatx4 acc[4][4];
#pragma unroll
    for (int m = 0; m < 4; ++m)
#pragma unroll
        for (int g = 0; g < 4; ++g)
            acc[m][g] = (floatx4){0.f, 0.f, 0.f, 0.f};

    for (int kt = 0; kt < 16; ++kt) {
        int k0 = kt * 64;
#pragma unroll
        for (int p = 0; p < 4; ++p) {
            int cch = tid + p * 256;            // 0..1023 chunks of 16B
            int row = cch >> 3, cslot = cch & 7;
            int csrc = cslot ^ (row & 7);       // inverse-swizzled source chunk
            int grow = brow + row; if (grow >= M) grow = M - 1;
            const unsigned short* g = A + (size_t)grow * KDIM + k0 + csrc * 8;
            __builtin_amdgcn_global_load_lds((const GLOBAL_AS void*)g,
                                             (LDS_AS void*)(sA + cch * 8), 16, 0, 0);
        }
#pragma unroll
        for (int p = 0; p < 4; ++p) {
            int cch = tid + p * 256;
            int row = cch >> 3, cslot = cch & 7;
            int csrc = cslot ^ (row & 7);
            const unsigned short* g = Bt + (size_t)(bcol + row) * KDIM + k0 + csrc * 8;
            __builtin_amdgcn_global_load_lds((const GLOBAL_AS void*)g,
                                             (LDS_AS void*)(sB + cch * 8), 16, 0, 0);
        }
        __syncthreads();

#pragma unroll
        for (int ks = 0; ks < 2; ++ks) {
            short8 af[4], bfr[4];
#pragma unroll
            for (int m = 0; m < 4; ++m) {
                int ra = wr + m * 16 + l15;
                af[m] = *(const short8*)(sA + ra * 64 + ((ks * 4 + l4) ^ (ra & 7)) * 8);
            }
#pragma unroll
            for (int g = 0; g < 4; ++g) {
                int rb = wc + g * 16 + l15;
                bfr[g] = *(const short8*)(sB + rb * 64 + ((ks * 4 + l4) ^ (rb & 7)) * 8);
            }
#pragma unroll
            for (int m = 0; m < 4; ++m)
#pragma unroll
                for (int g = 0; g < 4; ++g)
                    acc[m][g] = __builtin_amdgcn_mfma_f32_16x16x32_bf16(af[m], bfr[g], acc[m][g], 0, 0, 0);
        }
        __syncthreads();
    }

    // fused epilogue: this wave owns feature-group `group` for its 128-row slice
    int group = (bcol + wc) >> 6;          // 0..15
    int feat = (group << 4) | l15;         // 0..255
    float bc0 = b_conv[feat], bc1 = b_conv[FDIM + feat];
    float bc2 = b_conv[2 * FDIM + feat], bc3 = b_conv[3 * FDIM + feat];
    float bb0 = b[feat], bb1 = b[FDIM + feat];
    float bb2 = b[2 * FDIM + feat], bb3 = b[3 * FDIM + feat];
    float wci = w_c[feat], wcf = w_c[FDIM + feat], wco = w_c[2 * FDIM + feat];
    float wcl = Wcls[feat];

#pragma unroll
    for (int m = 0; m < 4; ++m) {
#pragma unroll
        for (int j = 0; j < 4; ++j) {
            int node = brow + wr + m * 16 + l4 * 4 + j;
            bool ok = node < M;
            int nidx = ok ? node : (M - 1);
            float cv = c[(size_t)nidx * FDIM + feat];
            float iv = sig(acc[m][0][j] + bc0 + wci * cv + bb0);
            float fv = sig(acc[m][1][j] + bc1 + wcf * cv + bb1);
            float tv = tanhf(acc[m][2][j] + bc2 + bb2);
            float cn = fv * cv + iv * tv;
            float ov = sig(acc[m][3][j] + bc3 + wco * cn + bb3);
            float hn = ov * tanhf(cn);
            if (ok) {
                out_h[(size_t)node * FDIM + feat] = hn;
                out_c[(size_t)node * FDIM + feat] = cn;
            }
            float pcls = fmaxf(hn, 0.f) * wcl;
#pragma unroll
            for (int s = 1; s < 16; s <<= 1) pcls += __shfl_xor(pcls, s);
            if (ok && l15 == 0) cls_part[(size_t)node * 16 + group] = pcls;
        }
    }
}

// classifier partial reduce: out_cls[i] = sum_g cls_part[i][g] + b_cls
__global__ void k_cls(const float* __restrict__ cls_part, const float* __restrict__ bcls,
                      float* __restrict__ out_cls, int n) {
    int i = blockIdx.x * blockDim.x + threadIdx.x;
    if (i >= n) return;
    const floatx4* p = (const floatx4*)(cls_part + (size_t)i * 16);
    floatx4 v0 = p[0], v1 = p[1], v2 = p[2], v3 = p[3];
    float s = v0[0] + v0[1] + v0[2] + v0[3] + v1[0] + v1[1] + v1[2] + v1[3]
            + v2[0] + v2[1] + v2[2] + v2[3] + v3[0] + v3[1] + v3[2] + v3[3];
    out_cls[i] = s + bcls[0];
}

// ---------------- launcher ----------------

extern "C" void kernel_launch(void* const* d_in, const int* in_sizes, int n_in,
                              void* d_out, int out_size, void* d_ws, size_t ws_size,
                              hipStream_t stream) {
    const float* x      = (const float*)d_in[0];
    const int*   eidx   = (const int*)d_in[1];
    const float* ew     = (const float*)d_in[2];
    const float* h      = (const float*)d_in[3];
    const float* c      = (const float*)d_in[4];
    const float* W      = (const float*)d_in[5];
    const float* theta  = (const float*)d_in[6];
    const float* b_conv = (const float*)d_in[7];
    const float* b      = (const float*)d_in[8];
    const float* w_c    = (const float*)d_in[9];
    const float* Wcls   = (const float*)d_in[10];
    const float* bcls   = (const float*)d_in[11];

    const int N = in_sizes[0] / FDIM;
    const int E = in_sizes[2];
    const int* src = eidx;
    const int* dst = eidx + E;

    char* ws = (char*)d_ws;
    size_t off = 0;
    auto alloc = [&](size_t bytes) -> void* {
        void* p = ws + off;
        off += (bytes + 255) & ~(size_t)255;
        return p;
    };
    unsigned short* A   = (unsigned short*)alloc((size_t)N * KDIM * 2);
    unsigned short* Bt  = (unsigned short*)alloc((size_t)KDIM * KDIM * 2);
    float* cls_part     = (float*)alloc((size_t)N * 16 * 4);
    float* deg          = (float*)alloc((size_t)N * 4);
    int*   cnt          = (int*)alloc((size_t)N * 4);
    int*   cur          = (int*)alloc((size_t)N * 4);
    float* dis          = (float*)alloc((size_t)N * 4);
    int*   offs         = (int*)alloc((size_t)(N + 1) * 4);
    int*   part         = (int*)alloc(64 * 4);
    int*   csr_src      = (int*)alloc((size_t)E * 4);
    float* csr_w        = (float*)alloc((size_t)E * 4);
    (void)ws_size; (void)n_in; (void)out_size;

    float* out_cls = (float*)d_out;
    float* out_h   = out_cls + N;
    float* out_c   = out_h + (size_t)N * FDIM;

    // zero deg/cnt/cur in one async memset (they are consecutive allocs)
    size_t zbytes = (size_t)((char*)(cur + N) - (char*)deg);
    hipMemsetAsync(deg, 0, zbytes, stream);

    int nsb = (N + 1023) / 1024;  // <= 64
    k_degcnt<<<(E + 255) / 256, 256, 0, stream>>>(src, dst, ew, deg, cnt, E);
    k_dis<<<(N + 255) / 256, 256, 0, stream>>>(deg, dis, N);
    k_scan1<<<nsb, 1024, 0, stream>>>(cnt, offs, part, N);
    k_scan2<<<nsb, 1024, 0, stream>>>(offs, part, N);
    k_scatter<<<(E + 255) / 256, 256, 0, stream>>>(src, dst, ew, dis, offs, cur, csr_src, csr_w, E);
    k_packA<<<(N * 64 + 255) / 256, 256, 0, stream>>>(x, h, A, N);
    k_packBt<<<(KDIM * KDIM + 255) / 256, 256, 0, stream>>>(W, theta, Bt);
    k_prop1<<<(N * 64 + 255) / 256, 256, 0, stream>>>(A, offs, csr_src, csr_w, N);
    k_prop2<<<(N * 64 + 255) / 256, 256, 0, stream>>>(A, h, offs, csr_src, csr_w, N);
    int mtiles = (N + 127) / 128;
    k_gemm<<<mtiles * 8, 256, 0, stream>>>(A, Bt, c, b_conv, b, w_c, Wcls,
                                           out_h, out_c, cls_part, N, mtiles);
    k_cls<<<(N + 255) / 256, 256, 0, stream>>>(cls_part, bcls, out_cls, N);
}